// Round 1
// baseline (704.129 us; speedup 1.0000x reference)
//
#include <hip/hip_runtime.h>

// ---------------------------------------------------------------------------
// WindowAttention on MI355X (gfx950).
// Pipeline: prep (weight transpose + bf16 cast into ws)
//        -> fused per-window attention (q/k/v GEMMs + QK^T + softmax + PV),
//           writes pre-projection output fp32 into d_out
//        -> proj GEMM in-place on d_out with split-bf16 (hi/lo) 3-pass MFMA
//           for near-fp32 precision (proj is the error-critical GEMM).
// All matmuls use v_mfma_f32_16x16x32_bf16.
// Fragment layouts (m89/m91-verified): A/B: elem j -> [lane&15][quad*8+j]
// (operands stored K-major, i.e. B as [N][K]); C/D: col=lane&15, row=quad*4+reg.
//
// R1 change vs 668.9us baseline: A-fragments of x1/x2 (head-invariant) are
// converted fp32->bf16 ONCE per block into registers (x1f[6], x2f[3][6])
// instead of re-loading + re-converting every head (6x redundant VALU +
// global fetch). Bias index math hoisted out of the head loop; bias folded
// into the QK^T MFMA C-initializer. Numerics unchanged.
// ---------------------------------------------------------------------------

typedef __attribute__((ext_vector_type(8))) short bf16x8;
typedef __attribute__((ext_vector_type(4))) float f32x4;

#define MFMA16(a, b, c) __builtin_amdgcn_mfma_f32_16x16x32_bf16((a), (b), (c), 0, 0, 0)

// ws layout (ushort elements)
#define WS_QKVT  0        // [192][192]  qkv_w^T   bf16
#define WS_QKV2T 36864    // [384][192]  qkv2_w^T  bf16
#define WS_PROJH 110592   // [192][192]  proj_w^T  hi bf16
#define WS_PROJL 147456   // [192][192]  proj_w^T  lo bf16
// total 184320 ushorts = 368,640 bytes of workspace

#define SCALE_Q 0.17677669529663687f   // 32^-0.5

__device__ __forceinline__ unsigned short f2bf(float f) {
  unsigned int u = __float_as_uint(f);
  u += 0x7fffu + ((u >> 16) & 1u);     // round-to-nearest-even
  return (unsigned short)(u >> 16);
}
__device__ __forceinline__ float bf2f(unsigned short s) {
  return __uint_as_float(((unsigned int)s) << 16);
}
// load 8 consecutive fp32 (32B, aligned) -> bf16x8 fragment
__device__ __forceinline__ bf16x8 cvt8(const float* __restrict__ p) {
  union { bf16x8 v; unsigned short s[8]; } U;
  float4 v0 = *(const float4*)p;
  float4 v1 = *(const float4*)(p + 4);
  U.s[0] = f2bf(v0.x); U.s[1] = f2bf(v0.y); U.s[2] = f2bf(v0.z); U.s[3] = f2bf(v0.w);
  U.s[4] = f2bf(v1.x); U.s[5] = f2bf(v1.y); U.s[6] = f2bf(v1.z); U.s[7] = f2bf(v1.w);
  return U.v;
}

// ---------------------------------------------------------------------------
// prep: W^T bf16 casts.  y = x @ W means B-operand needs W^T stored [n][k].
// ---------------------------------------------------------------------------
__global__ void prep_kernel(const float* __restrict__ qkv_w,
                            const float* __restrict__ qkv2_w,
                            const float* __restrict__ proj_w,
                            unsigned short* __restrict__ ws) {
  int t = blockIdx.x * 256 + threadIdx.x;
  if (t < 36864) {                       // qkv_w (192x192), reads coalesced
    int k = t / 192, n = t % 192;
    ws[WS_QKVT + n * 192 + k] = f2bf(qkv_w[t]);
  } else if (t < 110592) {               // qkv2_w (192x384)
    int u = t - 36864;
    int k = u / 384, n = u % 384;
    ws[WS_QKV2T + n * 192 + k] = f2bf(qkv2_w[u]);
  } else if (t < 147456) {               // proj_w (192x192) hi/lo split
    int u = t - 110592;
    int k = u / 192, n = u % 192;
    float p = proj_w[u];
    unsigned short hi = f2bf(p);
    ws[WS_PROJH + n * 192 + k] = hi;
    ws[WS_PROJL + n * 192 + k] = f2bf(p - bf2f(hi));
  }
}

// ---------------------------------------------------------------------------
// Fused attention: one block per window b. 256 threads = 4 waves.
// LDS carve (65,344 B dynamic, all offsets 16B-aligned, strides give 2-way
// (free) bank conflicts):
//   ksm  [196][40] bf16 @ 0       (15,680 B)  k for current head, K-major in d
//   vtm  [32][232] bf16 @ 15,680  (14,848 B)  v^T: [d][keypos], K-major in pos
//   atm  [64][232] bf16 @ 30,528  (29,696 B)  softmaxed attn, K-major in pos
//   qhm  [64][40]  bf16 @ 60,224  ( 5,120 B)  q for current head
// ---------------------------------------------------------------------------
__launch_bounds__(256, 2)
__global__ void attn_kernel(const float* __restrict__ x1,
                            const float* __restrict__ x2,
                            const float* __restrict__ qkv_b,
                            const float* __restrict__ qkv2_b,
                            const float* __restrict__ btab,   // [400][6]
                            const unsigned short* __restrict__ ws,
                            float* __restrict__ out) {
  extern __shared__ char smem[];
  unsigned short* ksm = (unsigned short*)(smem);
  unsigned short* vtm = (unsigned short*)(smem + 15680);
  unsigned short* atm = (unsigned short*)(smem + 30528);
  unsigned short* qhm = (unsigned short*)(smem + 60224);

  const int tid  = threadIdx.x;
  const int wave = tid >> 6;       // = m-tile for Q/QK/PV phases
  const int lane = tid & 63;
  const int l16  = lane & 15;
  const int quad = lane >> 4;
  const int b    = blockIdx.x;

  const float* x1b = x1 + (size_t)b * (49 * 192);
  const float* x2b = x2 + (size_t)b * (196 * 192);

  // Zero attn + v^T entirely once: pad cols (>=208) and pad rows (>=49 of
  // attn) must stay exactly 0.0 forever (PV K-loop runs to 224).
  {
    int* z = (int*)(smem + 30528);
    for (int i = tid; i < 29696 / 4; i += 256) z[i] = 0;
    int* z2 = (int*)(smem + 15680);
    for (int i = tid; i < 14848 / 4; i += 256) z2[i] = 0;
  }

  // Relative-position bias row term for this lane's 4 C-rows, pre-scaled by 6
  // (btab row stride). idx = (ih - jh + 13)*20 + (iw - jw + 13)
  //                        = (20*ih + iw + 273) - (20*jh + jw)
  int Pr6[4];
#pragma unroll
  for (int r = 0; r < 4; ++r) {
    int i = wave * 16 + quad * 4 + r;
    if (i > 48) i = 48;                  // pad rows: clamp (results unused)
    int ih = i / 7, iw = i - 7 * ih;
    Pr6[r] = (ih * 20 + iw + 273) * 6;
  }
  // Column term per n-tile, pre-scaled by 6. For nt<12 jc<196 always; only
  // nt==12 has pad lanes (valid iff l16<4) -- handled at use site.
  int qj6[13];
#pragma unroll
  for (int nt = 0; nt < 13; ++nt) {
    int jc = nt * 16 + l16;
    if (jc > 195) jc = 195;              // clamped value unused on pad lanes
    int jh = jc / 14, jw = jc - 14 * jh;
    qj6[nt] = (jh * 20 + jw) * 6;
  }

  // -------- Prologue: head-invariant A-fragments, converted ONCE -----------
  // x1f: this wave's q-GEMM A fragments (rows wave*16+l16, 6 K-chunks).
  bf16x8 x1f[6];
  {
    const int m = wave * 16 + l16;
    const bool mv = (m < 49);
#pragma unroll
    for (int kk = 0; kk < 6; ++kk) {
      if (mv) x1f[kk] = cvt8(x1b + m * 192 + kk * 32 + quad * 8);
      else    x1f[kk] = bf16x8{0, 0, 0, 0, 0, 0, 0, 0};
    }
  }
  // x2f: kv-GEMM A fragments for tiles mt = wave, wave+4, wave+8 (all rows
  // < 192 < 196: no pad check). Tile 12 (wave 0, 4 real rows) is recomputed
  // per head to save 24 VGPRs.
  bf16x8 x2f[3][6];
#pragma unroll
  for (int ti = 0; ti < 3; ++ti) {
    const int m = (wave + ti * 4) * 16 + l16;
#pragma unroll
    for (int kk = 0; kk < 6; ++kk)
      x2f[ti][kk] = cvt8(x2b + m * 192 + kk * 32 + quad * 8);
  }

  __syncthreads();   // zeroing visible before any LDS writes below

  for (int h = 0; h < 6; ++h) {
    // ---------------- Phase 1a: q_h = (x1 @ Wq_h + b) * SCALE ----------------
    {
      f32x4 acc0{0.f, 0.f, 0.f, 0.f}, acc1{0.f, 0.f, 0.f, 0.f};
#pragma unroll
      for (int kk = 0; kk < 6; ++kk) {
        const unsigned short* wq = ws + WS_QKVT + (h * 32 + l16) * 192 + kk * 32 + quad * 8;
        acc0 = MFMA16(x1f[kk], *(const bf16x8*)(wq), acc0);
        acc1 = MFMA16(x1f[kk], *(const bf16x8*)(wq + 16 * 192), acc1);
      }
      const float bia0 = qkv_b[h * 32 + l16];
      const float bia1 = qkv_b[h * 32 + 16 + l16];
#pragma unroll
      for (int r = 0; r < 4; ++r) {
        const int row = wave * 16 + quad * 4 + r;     // <= 63, in-bounds
        qhm[row * 40 + l16]      = f2bf((acc0[r] + bia0) * SCALE_Q);
        qhm[row * 40 + 16 + l16] = f2bf((acc1[r] + bia1) * SCALE_Q);
      }
    }
    // ---------------- Phase 1b: k_h, v_h = x2 @ Wkv_h + b --------------------
    const float bk0 = qkv2_b[h * 32 + l16];
    const float bk1 = qkv2_b[h * 32 + 16 + l16];
    const float bv0 = qkv2_b[192 + h * 32 + l16];
    const float bv1 = qkv2_b[192 + h * 32 + 16 + l16];
#pragma unroll
    for (int ti = 0; ti < 3; ++ti) {
      const int mt = wave + ti * 4;      // <= 11: every row real
      f32x4 acc0{0.f, 0.f, 0.f, 0.f}, acc1{0.f, 0.f, 0.f, 0.f};
      f32x4 acc2{0.f, 0.f, 0.f, 0.f}, acc3{0.f, 0.f, 0.f, 0.f};
#pragma unroll
      for (int kk = 0; kk < 6; ++kk) {
        const unsigned short* wk = ws + WS_QKV2T + (h * 32 + l16) * 192 + kk * 32 + quad * 8;
        acc0 = MFMA16(x2f[ti][kk], *(const bf16x8*)(wk), acc0);             // k 0-15
        acc1 = MFMA16(x2f[ti][kk], *(const bf16x8*)(wk + 16 * 192), acc1);  // k 16-31
        acc2 = MFMA16(x2f[ti][kk], *(const bf16x8*)(wk + 192 * 192), acc2); // v 0-15
        acc3 = MFMA16(x2f[ti][kk], *(const bf16x8*)(wk + 208 * 192), acc3); // v 16-31
      }
#pragma unroll
      for (int r = 0; r < 4; ++r) {
        const int row = mt * 16 + quad * 4 + r;       // < 192: unguarded
        ksm[row * 40 + l16]      = f2bf(acc0[r] + bk0);
        ksm[row * 40 + 16 + l16] = f2bf(acc1[r] + bk1);
        vtm[l16 * 232 + row]        = f2bf(acc2[r] + bv0);
        vtm[(16 + l16) * 232 + row] = f2bf(acc3[r] + bv1);
      }
    }
    if (wave == 0) {                     // ragged tile 12: rows 192-207
      f32x4 acc0{0.f, 0.f, 0.f, 0.f}, acc1{0.f, 0.f, 0.f, 0.f};
      f32x4 acc2{0.f, 0.f, 0.f, 0.f}, acc3{0.f, 0.f, 0.f, 0.f};
      const int m = 192 + l16;
      const bool mv = (m < 196);
#pragma unroll
      for (int kk = 0; kk < 6; ++kk) {
        const int k0 = kk * 32 + quad * 8;
        bf16x8 a;
        if (mv) a = cvt8(x2b + m * 192 + k0);
        else    a = bf16x8{0, 0, 0, 0, 0, 0, 0, 0};
        const unsigned short* wk = ws + WS_QKV2T + (h * 32 + l16) * 192 + k0;
        acc0 = MFMA16(a, *(const bf16x8*)(wk), acc0);
        acc1 = MFMA16(a, *(const bf16x8*)(wk + 16 * 192), acc1);
        acc2 = MFMA16(a, *(const bf16x8*)(wk + 192 * 192), acc2);
        acc3 = MFMA16(a, *(const bf16x8*)(wk + 208 * 192), acc3);
      }
#pragma unroll
      for (int r = 0; r < 4; ++r) {
        const int row = 192 + quad * 4 + r;
        if (row < 196) {
          ksm[row * 40 + l16]      = f2bf(acc0[r] + bk0);
          ksm[row * 40 + 16 + l16] = f2bf(acc1[r] + bk1);
        }
        // v^T rows 196-207 hold finite bias values, multiplied by attn==0
        // later; rows always < 208 so in-bounds of the 232 stride.
        vtm[l16 * 232 + row]        = f2bf(acc2[r] + bv0);
        vtm[(16 + l16) * 232 + row] = f2bf(acc3[r] + bv1);
      }
    }
    __syncthreads();

    // ---------------- Phase 2: logits = q k^T + bias, softmax ----------------
    f32x4 lg[13];
    {
      const int m = wave * 16 + l16;
      bf16x8 a = *(const bf16x8*)(qhm + m * 40 + quad * 8);
      // Bias (and key-pad mask) folded into the MFMA C-initializer.
#pragma unroll
      for (int nt = 0; nt < 12; ++nt) {
#pragma unroll
        for (int r = 0; r < 4; ++r) lg[nt][r] = btab[Pr6[r] - qj6[nt] + h];
      }
#pragma unroll
      for (int r = 0; r < 4; ++r)
        lg[12][r] = (l16 < 4) ? btab[Pr6[r] - qj6[12] + h] : -1e30f;
#pragma unroll
      for (int nt = 0; nt < 13; ++nt) {
        bf16x8 bb = *(const bf16x8*)(ksm + (nt * 16 + l16) * 40 + quad * 8);
        lg[nt] = MFMA16(a, bb, lg[nt]);
      }
      // row softmax: each row lives on the 16 lanes of one quad
#pragma unroll
      for (int r = 0; r < 4; ++r) {
        float mx = lg[0][r];
#pragma unroll
        for (int nt = 1; nt < 13; ++nt) mx = fmaxf(mx, lg[nt][r]);
        mx = fmaxf(mx, __shfl_xor(mx, 1));
        mx = fmaxf(mx, __shfl_xor(mx, 2));
        mx = fmaxf(mx, __shfl_xor(mx, 4));
        mx = fmaxf(mx, __shfl_xor(mx, 8));
        float s = 0.f;
#pragma unroll
        for (int nt = 0; nt < 13; ++nt) {
          float p = __expf(lg[nt][r] - mx);
          lg[nt][r] = p;
          s += p;
        }
        s += __shfl_xor(s, 1);
        s += __shfl_xor(s, 2);
        s += __shfl_xor(s, 4);
        s += __shfl_xor(s, 8);
        const float inv = 1.f / s;
        const int row = wave * 16 + quad * 4 + r;
        if (row < 49) {                      // pad rows stay zero in atm
#pragma unroll
          for (int nt = 0; nt < 13; ++nt)
            atm[row * 232 + nt * 16 + l16] = f2bf(lg[nt][r] * inv);
        }
      }
    }
    // ---------------- Phase 3: out_h = attn @ v  (K padded to 224) -----------
    {
      f32x4 o0{0.f, 0.f, 0.f, 0.f}, o1{0.f, 0.f, 0.f, 0.f};
      const int m = wave * 16 + l16;
#pragma unroll
      for (int kk = 0; kk < 7; ++kk) {
        const int k0 = kk * 32 + quad * 8;
        bf16x8 a  = *(const bf16x8*)(atm + m * 232 + k0);
        bf16x8 b0 = *(const bf16x8*)(vtm + l16 * 232 + k0);
        bf16x8 b1 = *(const bf16x8*)(vtm + (16 + l16) * 232 + k0);
        o0 = MFMA16(a, b0, o0);
        o1 = MFMA16(a, b1, o1);
      }
      // write pre-projection output fp32 into d_out (proj kernel is in-place)
#pragma unroll
      for (int r = 0; r < 4; ++r) {
        const int row = wave * 16 + quad * 4 + r;
        if (row < 49) {
          float* op = out + (size_t)b * 9408 + row * 192 + h * 32;
          op[l16]      = o0[r];
          op[16 + l16] = o1[r];
        }
      }
    }
    __syncthreads();   // protect ksm/vtm/qhm/atm rewrite by next head
  }
}

// ---------------------------------------------------------------------------
// proj: in-place on d_out. Each block owns 64 rows (50176 = 784*64 exactly).
// Split-bf16 3-pass MFMA: C += Ah*Bh + Ah*Bl + Al*Bh  (~fp32 quality).
// ---------------------------------------------------------------------------
__launch_bounds__(256, 2)
__global__ void proj_kernel(const float* __restrict__ proj_b,
                            const unsigned short* __restrict__ ws,
                            float* __restrict__ out) {
  extern __shared__ char smem[];
  float* aout = (float*)smem;            // [64][204] fp32 (stride 204: 2-way banks)
  const int tid  = threadIdx.x;
  const int wave = tid >> 6;
  const int lane = tid & 63;
  const int l16  = lane & 15;
  const int quad = lane >> 4;
  const size_t base = (size_t)blockIdx.x * 64 * 192;

  // stage this block's 64x192 fp32 slice (coalesced float4 reads)
  for (int i = tid; i < 64 * 192 / 4; i += 256) {
    int row = i / 48, col = (i - row * 48) * 4;
    float4 v = *(const float4*)(out + base + row * 192 + col);
    *(float4*)(aout + row * 204 + col) = v;
  }
  __syncthreads();

  f32x4 pacc[12];
#pragma unroll
  for (int nt = 0; nt < 12; ++nt) pacc[nt] = f32x4{0.f, 0.f, 0.f, 0.f};

  const int m = wave * 16 + l16;
#pragma unroll
  for (int kk = 0; kk < 6; ++kk) {
    const int k0 = kk * 32 + quad * 8;
    const float* ap = aout + m * 204 + k0;
    float4 v0 = *(const float4*)ap;
    float4 v1 = *(const float4*)(ap + 4);
    float f[8] = {v0.x, v0.y, v0.z, v0.w, v1.x, v1.y, v1.z, v1.w};
    union { bf16x8 v; unsigned short s[8]; } H, L;
#pragma unroll
    for (int j = 0; j < 8; ++j) {
      H.s[j] = f2bf(f[j]);
      L.s[j] = f2bf(f[j] - bf2f(H.s[j]));
    }
#pragma unroll
    for (int nt = 0; nt < 12; ++nt) {
      const unsigned short* bph = ws + WS_PROJH + (nt * 16 + l16) * 192 + k0;
      const unsigned short* bpl = ws + WS_PROJL + (nt * 16 + l16) * 192 + k0;
      bf16x8 bh = *(const bf16x8*)bph;
      bf16x8 bl = *(const bf16x8*)bpl;
      pacc[nt] = MFMA16(H.v, bh, pacc[nt]);
      pacc[nt] = MFMA16(H.v, bl, pacc[nt]);
      pacc[nt] = MFMA16(L.v, bh, pacc[nt]);
    }
  }
#pragma unroll
  for (int nt = 0; nt < 12; ++nt) {
    const float pb = proj_b[nt * 16 + l16];
#pragma unroll
    for (int r = 0; r < 4; ++r) {
      const int row = wave * 16 + quad * 4 + r;   // all 64 rows real
      out[base + row * 192 + nt * 16 + l16] = pacc[nt][r] + pb;
    }
  }
}

// ---------------------------------------------------------------------------
extern "C" void kernel_launch(void* const* d_in, const int* in_sizes, int n_in,
                              void* d_out, int out_size, void* d_ws, size_t ws_size,
                              hipStream_t stream) {
  const float* x1     = (const float*)d_in[0];
  const float* x2     = (const float*)d_in[1];
  const float* qkv_w  = (const float*)d_in[2];
  const float* qkv_b  = (const float*)d_in[3];
  const float* qkv2_w = (const float*)d_in[4];
  const float* qkv2_b = (const float*)d_in[5];
  const float* proj_w = (const float*)d_in[6];
  const float* proj_b = (const float*)d_in[7];
  const float* btab   = (const float*)d_in[8];
  unsigned short* ws  = (unsigned short*)d_ws;
  float* out          = (float*)d_out;
  (void)in_sizes; (void)n_in; (void)out_size; (void)ws_size;

  prep_kernel<<<dim3(576), dim3(256), 0, stream>>>(qkv_w, qkv2_w, proj_w, ws);
  attn_kernel<<<dim3(1024), dim3(256), 65344, stream>>>(x1, x2, qkv_b, qkv2_b,
                                                        btab, ws, out);
  proj_kernel<<<dim3(784), dim3(256), 52224, stream>>>(proj_b, ws, out);
}